// Round 8
// baseline (7789.862 us; speedup 1.0000x reference)
//
#include <hip/hip_runtime.h>
#include <hip/hip_bf16.h>
#include <math.h>

using bf16 = __hip_bfloat16;
using short8  = __attribute__((ext_vector_type(8))) short;
using float4v = __attribute__((ext_vector_type(4))) float;

#define B_   64
#define S_   12
#define N04  307
#define N07  883
#define N08  170
#define BN   (B_ * N04)        // 19648
#define HID  256
#define ENC  256
#define PRE  12
#define UOFF (N04 * HID)       // 78592 flat split point

// extractor geometry (plain constexpr — host reads these; __constant__ host shadow is zero-init)
constexpr int c_Mi[3]   = {N04, N07, N08};
constexpr int c_Kp[3]   = {320, 896, 192};
constexpr int c_Moff[3] = {0, N04, N04 + N07};
constexpr int c_Aoff[3] = {0, N04 * 320, N04 * 320 + N07 * 896};
constexpr int c_Cb[3]   = {0, 320, 320 + 896};
#define MTOT  (N04 + N07 + N08)   // 1360
#define H0T_LD 1408

// ---------------- static tensor tables ----------------
#define NT 38
constexpr int g_sz[NT] = {
    39296, 113024, 21760, 235776, 94249, 779689, 28900,
    32768, 256, 65536, 256, 256, 256, 1,
    32768, 256, 65536, 256, 256, 256, 1,
    32768, 256, 65536, 256, 256, 256, 1,
    131584, 512, 65792, 256, 65536, 1, 131072, 256, 3072, 12
};
struct Tables { int off[NT + 1]; int blk[NT + 1]; };
constexpr Tables mk_tables() {
    Tables t{};
    t.off[0] = 0; t.blk[0] = 0;
    for (int i = 0; i < NT; ++i) {
        t.off[i + 1] = t.off[i] + g_sz[i];
        t.blk[i + 1] = t.blk[i] + (g_sz[i] + 1023) / 1024;
    }
    return t;
}
constexpr Tables g_tbl = mk_tables();

static __device__ __forceinline__ float fsigmoid(float t) {
    return __builtin_amdgcn_rcpf(1.f + __expf(-t));
}
static __device__ __forceinline__ float ftanh(float t) {
    return 1.f - 2.f * __builtin_amdgcn_rcpf(__expf(2.f * t) + 1.f);
}

// MFMA B-fragment swizzle: (n,k) of BT[N][K] -> frag[ntile*KT+ktile][lane][8]
static __device__ __forceinline__ int frag_idx(int n, int k, int K) {
    return (((n >> 4) * (K >> 5) + (k >> 5)) << 9) + (((k >> 3) & 3) << 7) + ((n & 15) << 3) + (k & 7);
}

// ---------------- dtype sniffer ----------------
__global__ void sniff_kernel(const unsigned short* raw, int* flag)
{
    __shared__ int sh[256];
    int t = threadIdx.x, cnt = 0;
    for (int i = t; i < 2048; i += 256) {
        unsigned int w = ((unsigned int)raw[i]) << 16;
        float a = fabsf(__uint_as_float(w));
        if (a > 1e-3f && a < 100.f) cnt++;
    }
    sh[t] = cnt; __syncthreads();
    for (int off = 128; off > 0; off >>= 1) {
        if (t < off) sh[t] += sh[t + off];
        __syncthreads();
    }
    if (t == 0) *flag = (sh[0] > 1536) ? 1 : 0;
}

struct Ptrs { const void* p[NT]; };

__global__ __launch_bounds__(256) void convert_all(Ptrs a, float* arena, const int* flag)
{
    const int bf = *flag;
    int b = blockIdx.x;
    int t = 0;
    while (b >= g_tbl.blk[t + 1]) ++t;
    const int base = (b - g_tbl.blk[t]) * 1024;
    const int n = g_sz[t];
    const void* src = a.p[t];
    float* dst = arena + g_tbl.off[t];
#pragma unroll
    for (int k = 0; k < 4; ++k) {
        int j = base + k * 256 + threadIdx.x;
        if (j < n)
            dst[j] = bf ? __bfloat162float(((const bf16*)src)[j]) : ((const float*)src)[j];
    }
}

// ---------------- GRU weights in frag order ----------------
__global__ __launch_bounds__(256) void prep_weights(const float* w1, const float* w2, const float* wl,
                                                    bf16* WgT, bf16* WcT, bf16* WlT)
{
    int id = blockIdx.x * 256 + threadIdx.x;
    if (id < 131072) {                       // Wg: N=512,K=256; BT[n][k]=w1[1+k][n]
        int n = id >> 8, k = id & 255;
        WgT[frag_idx(n, k, 256)] = __float2bfloat16(w1[(size_t)(1 + k) * 512 + n]);
    } else if (id < 196608) {                // Wc
        int r = id - 131072; int n = r >> 8, k = r & 255;
        WcT[frag_idx(n, k, 256)] = __float2bfloat16(w2[(size_t)(1 + k) * 256 + n]);
    } else if (id < 262144) {                // Wl[:256]
        int r = id - 196608; int n = r >> 8, k = r & 255;
        WlT[frag_idx(n, k, 256)] = __float2bfloat16(wl[(size_t)k * 256 + n]);
    }
}

// ---------------- extractor operand prep (round-6 proven versions) ----------------
__global__ __launch_bounds__(256) void prep_adjB(const float* a4, const float* a7, const float* a8, bf16* adjB)
{
    int z = blockIdx.z;
    int Mi = c_Mi[z], Kp = c_Kp[z];
    int m = blockIdx.x;
    if (m >= Mi) return;
    const float* src = (z == 0) ? a4 : (z == 1) ? a7 : a8;
    bf16* dst = adjB + c_Aoff[z] + (size_t)m * Kp;
    for (int c = threadIdx.x; c < Kp; c += 256)
        dst[c] = (c < Mi) ? __float2bfloat16(src[(size_t)m * Mi + c]) : __float2bfloat16(0.f);
}

__global__ __launch_bounds__(256) void prep_transposes(
    const float* v4, const float* v7, const float* v8,
    const float* w1a, const float* w1b, const float* w1c,
    const float* w2a, const float* w2b, const float* w2c,
    const float* featW, const float* linW, const float* outW,
    bf16* vecB, bf16* W1T, bf16* W2T, bf16* featWT, bf16* linW2T, bf16* outWT)
{
    int id = blockIdx.x * 256 + threadIdx.x;
    if (id < 174080) {                       // vecB [1360][128]
        int r = id >> 7, c = id & 127;
        float v = (r < N04) ? v4[(size_t)r * 128 + c]
                : (r < N04 + N07) ? v7[(size_t)(r - N04) * 128 + c]
                : v8[(size_t)(r - N04 - N07) * 128 + c];
        vecB[id] = __float2bfloat16(v);
    } else if (id < 174080 + 98304) {        // W1T [3][256][128] row-major BT
        int r = id - 174080; int z = r >> 15; int rem = r & 32767;
        int n = rem >> 7, k = rem & 127;
        const float* w = (z == 0) ? w1a : (z == 1) ? w1b : w1c;
        W1T[r] = __float2bfloat16(w[(size_t)k * 256 + n]);
    } else if (id < 272384 + 196608) {       // W2T [3][256][256]
        int r = id - 272384; int z = r >> 16; int rem = r & 65535;
        int n = rem >> 8, k = rem & 255;
        const float* w = (z == 0) ? w2a : (z == 1) ? w2b : w2c;
        W2T[r] = __float2bfloat16(w[(size_t)k * 256 + n]);
    } else if (id < 468992 + 65536) {        // featWT
        int r = id - 468992; int n = r >> 8, k = r & 255;
        featWT[r] = __float2bfloat16(featW[(size_t)k * 256 + n]);
    } else if (id < 534528 + 65536) {        // linW2T
        int r = id - 534528; int n = r >> 8, k = r & 255;
        linW2T[r] = __float2bfloat16(linW[(size_t)(256 + k) * 256 + n]);
    } else if (id < 600064 + 16384) {        // outWT [64][256], rows 12..63 zero
        int r = id - 600064; int p = r >> 8, k = r & 255;
        outWT[r] = __float2bfloat16((p < PRE) ? outW[(size_t)k * PRE + p] : 0.f);
    }
}
#define PREP_T_TOT (600064 + 16384)

// ---------------- 64x64-tile MFMA GEMM (round-6 proven) ----------------
struct GemmZ {
    const unsigned short* A[3];
    const unsigned short* BT[3];
    int M[3]; int K[3]; int lda[3]; int ldb[3];
};

template <typename EP>
__global__ __launch_bounds__(256) void gemm_mfma64(GemmZ p, int Nv, EP ep)
{
    const int z = blockIdx.z;
    const int M = p.M[z], K = p.K[z], lda = p.lda[z], ldb = p.ldb[z];
    const int m0 = blockIdx.x * 64;
    const int n0 = blockIdx.y * 64;
    if (m0 >= M) return;
    __shared__ __align__(16) unsigned short As[64 * 72];
    __shared__ __align__(16) unsigned short Bs[64 * 72];
    const int t = threadIdx.x;
    const int srow  = t >> 2;
    const int skoff = (t & 3) * 16;
    const int lane = t & 63;
    const int w  = t >> 6;
    const int wm = (w & 1) * 32;
    const int wn = (w >> 1) * 32;
    const int l15 = lane & 15;
    const int l4  = lane >> 4;

    float4v acc[2][2];
#pragma unroll
    for (int i = 0; i < 2; ++i)
#pragma unroll
        for (int j = 0; j < 2; ++j) acc[i][j] = (float4v)(0.f);

    const int gm = m0 + srow;
    const bool avalid = (gm < M);
    const unsigned short* aptr = p.A[z]  + (size_t)gm * lda + skoff;
    const unsigned short* bptr = p.BT[z] + (size_t)(n0 + srow) * ldb + skoff;
    unsigned short* asw = &As[srow * 72 + skoff];
    unsigned short* bsw = &Bs[srow * 72 + skoff];
    const uint4 z4 = {0, 0, 0, 0};

    for (int kt = 0; kt < K; kt += 64) {
        uint4 av0 = avalid ? *(const uint4*)(aptr + kt)     : z4;
        uint4 av1 = avalid ? *(const uint4*)(aptr + kt + 8) : z4;
        uint4 bv0 = *(const uint4*)(bptr + kt);
        uint4 bv1 = *(const uint4*)(bptr + kt + 8);
        __syncthreads();
        *(uint4*)(asw)     = av0;
        *(uint4*)(asw + 8) = av1;
        *(uint4*)(bsw)     = bv0;
        *(uint4*)(bsw + 8) = bv1;
        __syncthreads();
#pragma unroll
        for (int ks = 0; ks < 2; ++ks) {
            short8 af[2], bq[2];
#pragma unroll
            for (int mi = 0; mi < 2; ++mi)
                af[mi] = *(const short8*)&As[(wm + mi * 16 + l15) * 72 + ks * 32 + l4 * 8];
#pragma unroll
            for (int ni = 0; ni < 2; ++ni)
                bq[ni] = *(const short8*)&Bs[(wn + ni * 16 + l15) * 72 + ks * 32 + l4 * 8];
#pragma unroll
            for (int mi = 0; mi < 2; ++mi)
#pragma unroll
                for (int ni = 0; ni < 2; ++ni)
                    acc[mi][ni] = __builtin_amdgcn_mfma_f32_16x16x32_bf16(af[mi], bq[ni], acc[mi][ni], 0, 0, 0);
        }
    }
#pragma unroll
    for (int mi = 0; mi < 2; ++mi) {
#pragma unroll
        for (int r = 0; r < 4; ++r) {
            int m = m0 + wm + mi * 16 + l4 * 4 + r;
            if (m >= M) continue;
#pragma unroll
            for (int ni = 0; ni < 2; ++ni) {
                int n = n0 + wn + ni * 16 + l15;
                if (n < Nv) ep(z, m, n, acc[mi][ni][r]);
            }
        }
    }
}

// ---------------- extractor epilogues ----------------
struct EPg1 {
    const float* b1[3]; float* h0F; bf16* h0T;
    __device__ void operator()(int z, int m, int n, float v) const {
        v += b1[z][n];
        int gr = c_Moff[z] + m;
        h0F[(size_t)gr * 256 + n] = v;
        h0T[(size_t)n * H0T_LD + c_Cb[z] + m] = __float2bfloat16(v);
    }
};
struct EPg2 {
    const float* deg; const float* h0F; float* h1F; const float* eps[3];
    __device__ void operator()(int z, int m, int n, float v) const {
        int gr = c_Moff[z] + m;
        h1F[(size_t)gr * 256 + n] = v / deg[gr] + eps[z][0] * h0F[(size_t)gr * 256 + n];
    }
};
struct EPg3 {
    const float* b2[3]; void* outbase; size_t ooff[3]; const int* flag; bf16* f4B;
    __device__ void operator()(int z, int m, int n, float v) const {
        v += b2[z][n];
        size_t i = ooff[z] + (size_t)m * 256 + n;
        if (*flag) ((bf16*)outbase)[i] = __float2bfloat16(v);
        else       ((float*)outbase)[i] = v;
        if (z == 0) f4B[(size_t)m * 256 + n] = __float2bfloat16(v);
    }
};
struct EPfp2a {
    const float* sb; bf16* fpreB;
    __device__ void operator()(int z, int m, int n, float v) const {
        fpreB[(size_t)m * 256 + n] = __float2bfloat16(v + sb[0]);
    }
};
struct EPfp2b {
    float* fp2;
    __device__ void operator()(int z, int m, int n, float v) const {
        fp2[(size_t)m * 256 + n] = v;
    }
};
struct EPpred {
    const float* ob; void* outbase; const int* flag;
    __device__ void operator()(int z, int m, int n, float v) const {
        v += ob[n];
        size_t i = (size_t)m * PRE + n;
        if (*flag) ((bf16*)outbase)[i] = __float2bfloat16(v);
        else       ((float*)outbase)[i] = v;
    }
};

// ---------------- fused persistent GRU ----------------
// 256 blocks x 512 threads; 4 blocks per batch; per-batch atomic barrier.
// Per phase: B-frags in registers (loaded once), A staged in LDS 64-row chunks.
__device__ __forceinline__ void gru_barrier(unsigned* cnt, int b, unsigned target)
{
    __syncthreads();
    __threadfence();                       // release: flush this block's stores
    if (threadIdx.x == 0) {
        atomicAdd(&cnt[b], 1u);
        int guard = 0;
        while (atomicAdd(&cnt[b], 0u) < 4u * target) {
            __builtin_amdgcn_s_sleep(8);
            if (++guard > (1 << 26)) break;   // safety: degrade, don't hang
        }
    }
    __syncthreads();
    __threadfence();                       // acquire: invalidate stale cache
    __syncthreads();
}

template <int PH>
__device__ __forceinline__ void gru_phase(
    int b, int q, int w, int lane, int l15, int l4, int s,
    unsigned short* As, const unsigned short* Bf, const bf16* Asrc,
    const float* bias, const float* wrow0, const float* featF,
    const bf16* hc, bf16* rh, bf16* ub, bf16* uhc, bf16* hn,
    const float* lb, const float* fp2)
{
    constexpr int NPAIRS = (PH == 0) ? 4 : 2;   // n-tile-pairs per block
    constexpr int MSTR   = (PH == 0) ? 2 : 4;   // m-tile stride per wave
    constexpr int NTB    = (PH == 0) ? 8 : 4;   // n-tiles per block
    const int pairIdx = w & (NPAIRS - 1);
    const int mph = w / NPAIRS;
    const int nt0 = q * NTB + pairIdx * 2;
    short8 bq[2][8];
#pragma unroll
    for (int t = 0; t < 2; ++t)
#pragma unroll
        for (int kt = 0; kt < 8; ++kt)
            bq[t][kt] = *(const short8*)(Bf + (((size_t)((nt0 + t) * 8 + kt)) << 9) + lane * 8);
    const int rowbase = b * N04;
    const int tid = threadIdx.x;
    for (int c = 0; c < 5; ++c) {
        __syncthreads();
#pragma unroll
        for (int i = 0; i < 4; ++i) {
            int u = tid + i * 512;
            int r = u >> 5, col = u & 31;
            uint4 v = *(const uint4*)((const unsigned short*)Asrc + (size_t)(rowbase + c * 64 + r) * 256 + col * 8);
            *(uint4*)(&As[r * 264 + col * 8]) = v;
        }
        __syncthreads();
        int mtEnd = c * 4 + 4; if (mtEnd > 20) mtEnd = 20;
        for (int mt = c * 4 + mph; mt < mtEnd; mt += MSTR) {
            int mloc = (mt - c * 4) * 16;
            float4v acc0 = (float4v)(0.f), acc1 = (float4v)(0.f);
#pragma unroll
            for (int kt = 0; kt < 8; ++kt) {
                short8 a = *(const short8*)&As[(mloc + l15) * 264 + kt * 32 + l4 * 8];
                acc0 = __builtin_amdgcn_mfma_f32_16x16x32_bf16(a, bq[0][kt], acc0, 0, 0, 0);
                acc1 = __builtin_amdgcn_mfma_f32_16x16x32_bf16(a, bq[1][kt], acc1, 0, 0, 0);
            }
#pragma unroll
            for (int r = 0; r < 4; ++r) {
                int mrow = mt * 16 + l4 * 4 + r;
                if (mrow >= N04) continue;
                int nn = mrow;
                float x = 0.f;
                if (PH < 2) x = featF[((size_t)b * S_ + s) * N04 + nn];
                size_t base = (size_t)b * UOFF;
#pragma unroll
                for (int t = 0; t < 2; ++t) {
                    int ncol = (nt0 + t) * 16 + l15;
                    float v = (t == 0) ? acc0[r] : acc1[r];
                    if (PH == 0) {
                        float g = fsigmoid(v + bias[ncol] + x * wrow0[ncol]);
                        int p = nn * 512 + ncol;
                        if (p < UOFF) {
                            size_t idx = base + p;
                            rh[idx] = __float2bfloat16(g * __bfloat162float(hc[idx]));
                        } else {
                            ub[base + (p - UOFF)] = __float2bfloat16(g);
                        }
                    } else if (PH == 1) {
                        float cc = ftanh(v + bias[ncol] + x * wrow0[ncol]);
                        size_t idx = base + (size_t)nn * 256 + ncol;
                        float uu = __bfloat162float(ub[idx]);
                        float hh = __bfloat162float(hc[idx]);
                        uhc[idx] = __float2bfloat16(uu * hh + (1.f - uu) * cc);
                    } else {
                        size_t idx = base + (size_t)nn * 256 + ncol;
                        hn[idx] = __float2bfloat16(v + lb[ncol] + fp2[(size_t)nn * 256 + ncol]);
                    }
                }
            }
        }
    }
}

__global__ __launch_bounds__(512, 1) void gru_fused(
    const unsigned short* WgT, const unsigned short* WcT, const unsigned short* WlT,
    const float* gb1, const float* gw1r0, const float* gb2, const float* gw2r0,
    const float* lb, const float* fp2, const float* featF,
    bf16* hA, bf16* hBv, bf16* rh, bf16* ub, bf16* uhc, unsigned* cnt)
{
    __shared__ __align__(16) unsigned short As[64 * 264];
    const int blk = blockIdx.x;
    const int b = blk >> 2, q = blk & 3;
    const int tid = threadIdx.x;
    const int w = tid >> 6, lane = tid & 63;
    const int l15 = lane & 15, l4 = lane >> 4;
    bf16* hc = hA; bf16* hn = hBv;
    unsigned phase = 0;
    for (int s = 0; s < S_; ++s) {
        gru_phase<0>(b, q, w, lane, l15, l4, s, As, WgT, hc,  gb1, gw1r0, featF, hc, rh, ub, uhc, hn, lb, fp2);
        gru_barrier(cnt, b, ++phase);
        gru_phase<1>(b, q, w, lane, l15, l4, s, As, WcT, rh,  gb2, gw2r0, featF, hc, rh, ub, uhc, hn, lb, fp2);
        gru_barrier(cnt, b, ++phase);
        gru_phase<2>(b, q, w, lane, l15, l4, s, As, WlT, uhc, nullptr, nullptr, featF, hc, rh, ub, uhc, hn, lb, fp2);
        gru_barrier(cnt, b, ++phase);
        bf16* tt = hc; hc = hn; hn = tt;
    }
}

// ---------------- merged small kernels ----------------
__global__ void deg_all(const float* a4, const float* a7, const float* a8, float* deg)
{
    int z = blockIdx.z;
    int Mi = c_Mi[z];
    int row = blockIdx.x;
    if (row >= Mi) return;
    const float* adj = (z == 0) ? a4 : (z == 1) ? a7 : a8;
    float s = 0.f;
    for (int j = threadIdx.x; j < Mi; j += 64) s += adj[(size_t)row * Mi + j];
#pragma unroll
    for (int off = 32; off > 0; off >>= 1) s += __shfl_down(s, off, 64);
    if (threadIdx.x == 0) deg[c_Moff[z] + row] = s;
}

__global__ __launch_bounds__(256) void stats_all(const float* h1F, float* mu, float* rstd)
{
    int z = blockIdx.z;
    int Mi = c_Mi[z], moff = c_Moff[z];
    int j = blockIdx.x;
    int t = threadIdx.x;
    float s = 0.f, ss = 0.f;
    for (int i = t; i < Mi; i += 256) {
        float v = h1F[(size_t)(moff + i) * 256 + j];
        s += v; ss += v * v;
    }
    __shared__ float sh[256], sh2[256];
    sh[t] = s; sh2[t] = ss;
    __syncthreads();
    for (int off = 128; off > 0; off >>= 1) {
        if (t < off) { sh[t] += sh[t + off]; sh2[t] += sh2[t + off]; }
        __syncthreads();
    }
    if (t == 0) {
        float m = sh[0] / (float)Mi;
        float var = sh2[0] / (float)Mi - m * m;
        mu[z * 256 + j] = m;
        rstd[z * 256 + j] = rsqrtf(var + 1e-5f);
    }
}

__global__ __launch_bounds__(256) void norm_all(const float* h1F, const float* mu, const float* rstd,
                                                const float* ga, const float* gb, const float* gc,
                                                const float* ba, const float* bb, const float* bc,
                                                bf16* nh1B)
{
    int r = blockIdx.x;
    int n = threadIdx.x;
    int z = (r < N04) ? 0 : (r < N04 + N07) ? 1 : 2;
    const float* g  = (z == 0) ? ga : (z == 1) ? gb : gc;
    const float* bt = (z == 0) ? ba : (z == 1) ? bb : bc;
    float v = (h1F[(size_t)r * 256 + n] - mu[z * 256 + n]) * rstd[z * 256 + n] * g[n] + bt[n];
    nh1B[(size_t)r * 256 + n] = __float2bfloat16(v);
}

extern "C" void kernel_launch(void* const* d_in, const int* in_sizes, int n_in,
                              void* d_out, int out_size, void* d_ws, size_t ws_size,
                              hipStream_t stream)
{
    char* wp = (char*)d_ws;
    auto carve = [&](size_t bytes) -> void* {
        void* p = (void*)wp;
        wp += (bytes + 255) & ~(size_t)255;
        return p;
    };
    float* arena = (float*)carve((size_t)g_tbl.off[NT] * 4);
    int*   flag  = (int*)carve(256);
    unsigned* cnt = (unsigned*)carve(256);
    // +16-row pad: MFMA a-frag loads of the last (partial) m-tile read past row 306
    bf16*  hb_a  = (bf16*)carve((size_t)(BN + 16) * HID * 2);
    bf16*  hb_b  = (bf16*)carve((size_t)(BN + 16) * HID * 2);
    bf16*  rh    = (bf16*)carve((size_t)(BN + 16) * HID * 2);
    bf16*  uhc   = (bf16*)carve((size_t)(BN + 16) * HID * 2);
    bf16*  ubufB = (bf16*)carve((size_t)(BN + 16) * HID * 2);
    bf16*  WgT   = (bf16*)carve((size_t)512 * 256 * 2);
    bf16*  WcT   = (bf16*)carve((size_t)256 * 256 * 2);
    bf16*  WlT   = (bf16*)carve((size_t)256 * 256 * 2);
    bf16*  vecB  = (bf16*)carve((size_t)MTOT * 128 * 2);
    bf16*  adjB  = (bf16*)carve((size_t)(N04 * 320 + N07 * 896 + N08 * 192) * 2);
    bf16*  W1T   = (bf16*)carve((size_t)3 * 256 * 128 * 2);
    bf16*  W2T   = (bf16*)carve((size_t)3 * 256 * 256 * 2);
    bf16*  featWT= (bf16*)carve((size_t)256 * 256 * 2);
    bf16*  linW2T= (bf16*)carve((size_t)256 * 256 * 2);
    bf16*  outWT = (bf16*)carve((size_t)64 * 256 * 2);
    float* h0F   = (float*)carve((size_t)MTOT * 256 * 4);
    bf16*  h0T   = (bf16*)carve((size_t)256 * H0T_LD * 2);
    float* h1F   = (float*)carve((size_t)MTOT * 256 * 4);
    bf16*  nh1B  = (bf16*)carve((size_t)MTOT * 256 * 2);
    float* degb  = (float*)carve((size_t)MTOT * 4);
    float* mub   = (float*)carve(3 * 256 * 4);
    float* rstdb = (float*)carve(3 * 256 * 4);
    bf16*  f4B   = (bf16*)carve((size_t)N04 * 256 * 2);
    bf16*  fpreB = (bf16*)carve((size_t)N04 * 256 * 2);
    float* fp2   = (float*)carve((size_t)N04 * 256 * 4);

    // --- dtype sniff + canonical fp32 conversion ---
    sniff_kernel<<<1, 256, 0, stream>>>((const unsigned short*)d_in[0], flag);
    Ptrs ptrs;
    for (int i = 0; i < NT; ++i) ptrs.p[i] = d_in[i];
    convert_all<<<g_tbl.blk[NT], 256, 0, stream>>>(ptrs, arena, flag);

    auto A = [&](int i) -> const float* { return arena + g_tbl.off[i]; };

    // --- operand prep ---
    prep_weights<<<1024, 256, 0, stream>>>(A(28), A(30), A(34), WgT, WcT, WlT);
    prep_adjB<<<dim3(N07, 1, 3), 256, 0, stream>>>(A(4), A(5), A(6), adjB);
    prep_transposes<<<(PREP_T_TOT + 255) / 256, 256, 0, stream>>>(
        A(0), A(1), A(2), A(7), A(14), A(21), A(9), A(16), A(23),
        A(32), A(34), A(36), vecB, W1T, W2T, featWT, linW2T, outWT);

    hipMemsetAsync(hb_a, 0, (size_t)BN * HID * 2, stream);
    hipMemsetAsync(h0T, 0, (size_t)256 * H0T_LD * 2, stream);
    hipMemsetAsync(cnt, 0, 256, stream);

    const size_t o_f4 = (size_t)B_ * N04 * PRE;
    const size_t o_f7 = o_f4 + (size_t)N04 * ENC;
    const size_t o_f8 = o_f7 + (size_t)N07 * ENC;

    // --- deg ---
    deg_all<<<dim3(N07, 1, 3), 64, 0, stream>>>(A(4), A(5), A(6), degb);

    // --- E1: h0 = vec@W1 + b1 ---
    {
        GemmZ p;
        for (int z = 0; z < 3; ++z) {
            p.A[z] = (const unsigned short*)(vecB + (size_t)c_Moff[z] * 128);
            p.BT[z] = (const unsigned short*)(W1T + (size_t)z * 256 * 128);
            p.M[z] = c_Mi[z]; p.K[z] = 128; p.lda[z] = 128; p.ldb[z] = 128;
        }
        EPg1 ep{{A(8), A(15), A(22)}, h0F, h0T};
        gemm_mfma64<<<dim3(14, 4, 3), 256, 0, stream>>>(p, 256, ep);
    }
    // --- E2: h1 = (adj@h0)/deg + eps*h0 ---
    {
        GemmZ p;
        for (int z = 0; z < 3; ++z) {
            p.A[z] = (const unsigned short*)(adjB + c_Aoff[z]);
            p.BT[z] = (const unsigned short*)(h0T + c_Cb[z]);
            p.M[z] = c_Mi[z]; p.K[z] = c_Kp[z]; p.lda[z] = c_Kp[z]; p.ldb[z] = H0T_LD;
        }
        EPg2 ep{degb, h0F, h1F, {A(13), A(20), A(27)}};
        gemm_mfma64<<<dim3(14, 4, 3), 256, 0, stream>>>(p, 256, ep);
    }
    // --- BN stats + normalize ---
    stats_all<<<dim3(256, 1, 3), 256, 0, stream>>>(h1F, mub, rstdb);
    norm_all<<<MTOT, 256, 0, stream>>>(h1F, mub, rstdb, A(11), A(18), A(25), A(12), A(19), A(26), nh1B);
    // --- E3: f = nh1@W2 + b2 ---
    {
        GemmZ p;
        for (int z = 0; z < 3; ++z) {
            p.A[z] = (const unsigned short*)(nh1B + (size_t)c_Moff[z] * 256);
            p.BT[z] = (const unsigned short*)(W2T + (size_t)z * 256 * 256);
            p.M[z] = c_Mi[z]; p.K[z] = 256; p.lda[z] = 256; p.ldb[z] = 256;
        }
        EPg3 ep{{A(10), A(17), A(24)}, d_out, {o_f4, o_f7, o_f8}, flag, f4B};
        gemm_mfma64<<<dim3(14, 4, 3), 256, 0, stream>>>(p, 256, ep);
    }
    // --- fp2 = (f4@featW + featb) @ linW[256:512] ---
    {
        GemmZ p{};
        p.A[0] = (const unsigned short*)f4B; p.BT[0] = (const unsigned short*)featWT;
        p.M[0] = N04; p.K[0] = 256; p.lda[0] = 256; p.ldb[0] = 256;
        gemm_mfma64<<<dim3(5, 4, 1), 256, 0, stream>>>(p, 256, EPfp2a{A(33), fpreB});
        p.A[0] = (const unsigned short*)fpreB; p.BT[0] = (const unsigned short*)linW2T;
        gemm_mfma64<<<dim3(5, 4, 1), 256, 0, stream>>>(p, 256, EPfp2b{fp2});
    }

    // --- GRU: single fused persistent kernel (12 steps x 3 phases) ---
    gru_fused<<<256, 512, 0, stream>>>(
        (const unsigned short*)WgT, (const unsigned short*)WcT, (const unsigned short*)WlT,
        A(29), A(28), A(31), A(30), A(35), fp2, A(3),
        hb_a, hb_b, rh, ubufB, uhc, cnt);

    // --- pred = h_final@outW + outb (final h is in hb_a after 12 ping-pongs) ---
    {
        GemmZ p{};
        p.A[0] = (const unsigned short*)hb_a; p.BT[0] = (const unsigned short*)outWT;
        p.M[0] = BN; p.K[0] = 256; p.lda[0] = 256; p.ldb[0] = 256;
        gemm_mfma64<<<dim3(BN / 64 + 1, 1, 1), 256, 0, stream>>>(p, PRE, EPpred{A(37), d_out, flag});
    }
}

// Round 9
// 2145.726 us; speedup vs baseline: 3.6304x; 3.6304x over previous
//
#include <hip/hip_runtime.h>
#include <hip/hip_bf16.h>
#include <math.h>

using bf16 = __hip_bfloat16;
using short8  = __attribute__((ext_vector_type(8))) short;
using float4v = __attribute__((ext_vector_type(4))) float;

#define B_   64
#define S_   12
#define N04  307
#define N07  883
#define N08  170
#define BN   (B_ * N04)        // 19648 = 307*64
#define HID  256
#define ENC  256
#define PRE  12
#define UOFF (N04 * HID)       // 78592 flat split point

// extractor geometry (plain constexpr — host reads these; __constant__ host shadow is zero-init)
constexpr int c_Mi[3]   = {N04, N07, N08};
constexpr int c_Kp[3]   = {320, 896, 192};
constexpr int c_Moff[3] = {0, N04, N04 + N07};
constexpr int c_Aoff[3] = {0, N04 * 320, N04 * 320 + N07 * 896};
constexpr int c_Cb[3]   = {0, 320, 320 + 896};
#define MTOT  (N04 + N07 + N08)   // 1360
#define H0T_LD 1408

// ---------------- static tensor tables ----------------
#define NT 38
constexpr int g_sz[NT] = {
    39296, 113024, 21760, 235776, 94249, 779689, 28900,
    32768, 256, 65536, 256, 256, 256, 1,
    32768, 256, 65536, 256, 256, 256, 1,
    32768, 256, 65536, 256, 256, 256, 1,
    131584, 512, 65792, 256, 65536, 1, 131072, 256, 3072, 12
};
struct Tables { int off[NT + 1]; int blk[NT + 1]; };
constexpr Tables mk_tables() {
    Tables t{};
    t.off[0] = 0; t.blk[0] = 0;
    for (int i = 0; i < NT; ++i) {
        t.off[i + 1] = t.off[i] + g_sz[i];
        t.blk[i + 1] = t.blk[i] + (g_sz[i] + 1023) / 1024;
    }
    return t;
}
constexpr Tables g_tbl = mk_tables();

static __device__ __forceinline__ float fsigmoid(float t) {
    return __builtin_amdgcn_rcpf(1.f + __expf(-t));
}
static __device__ __forceinline__ float ftanh(float t) {
    return 1.f - 2.f * __builtin_amdgcn_rcpf(__expf(2.f * t) + 1.f);
}

// ---------------- dtype sniffer ----------------
__global__ void sniff_kernel(const unsigned short* raw, int* flag)
{
    __shared__ int sh[256];
    int t = threadIdx.x, cnt = 0;
    for (int i = t; i < 2048; i += 256) {
        unsigned int w = ((unsigned int)raw[i]) << 16;
        float a = fabsf(__uint_as_float(w));
        if (a > 1e-3f && a < 100.f) cnt++;
    }
    sh[t] = cnt; __syncthreads();
    for (int off = 128; off > 0; off >>= 1) {
        if (t < off) sh[t] += sh[t + off];
        __syncthreads();
    }
    if (t == 0) *flag = (sh[0] > 1536) ? 1 : 0;
}

struct Ptrs { const void* p[NT]; };

__global__ __launch_bounds__(256) void convert_all(Ptrs a, float* arena, const int* flag)
{
    const int bf = *flag;
    int b = blockIdx.x;
    int t = 0;
    while (b >= g_tbl.blk[t + 1]) ++t;
    const int base = (b - g_tbl.blk[t]) * 1024;
    const int n = g_sz[t];
    const void* src = a.p[t];
    float* dst = arena + g_tbl.off[t];
#pragma unroll
    for (int k = 0; k < 4; ++k) {
        int j = base + k * 256 + threadIdx.x;
        if (j < n)
            dst[j] = bf ? __bfloat162float(((const bf16*)src)[j]) : ((const float*)src)[j];
    }
}

// ---------------- GRU weights: plain row-major BT [N][K] (round-6 proven) ----------------
__global__ __launch_bounds__(256) void prep_weights(const float* w1, const float* w2, const float* wl,
                                                    bf16* WgT, bf16* WcT, bf16* WlT)
{
    int id = blockIdx.x * 256 + threadIdx.x;
    if (id < 131072) {
        int n = id >> 8, k = id & 255;
        WgT[id] = __float2bfloat16(w1[(size_t)(1 + k) * 512 + n]);
    } else if (id < 196608) {
        int r = id - 131072; int n = r >> 8, k = r & 255;
        WcT[r] = __float2bfloat16(w2[(size_t)(1 + k) * 256 + n]);
    } else if (id < 262144) {
        int r = id - 196608; int n = r >> 8, k = r & 255;
        WlT[r] = __float2bfloat16(wl[(size_t)k * 256 + n]);
    }
}

// ---------------- extractor operand prep (round-6 proven) ----------------
__global__ __launch_bounds__(256) void prep_adjB(const float* a4, const float* a7, const float* a8, bf16* adjB)
{
    int z = blockIdx.z;
    int Mi = c_Mi[z], Kp = c_Kp[z];
    int m = blockIdx.x;
    if (m >= Mi) return;
    const float* src = (z == 0) ? a4 : (z == 1) ? a7 : a8;
    bf16* dst = adjB + c_Aoff[z] + (size_t)m * Kp;
    for (int c = threadIdx.x; c < Kp; c += 256)
        dst[c] = (c < Mi) ? __float2bfloat16(src[(size_t)m * Mi + c]) : __float2bfloat16(0.f);
}

__global__ __launch_bounds__(256) void prep_transposes(
    const float* v4, const float* v7, const float* v8,
    const float* w1a, const float* w1b, const float* w1c,
    const float* w2a, const float* w2b, const float* w2c,
    const float* featW, const float* linW, const float* outW,
    bf16* vecB, bf16* W1T, bf16* W2T, bf16* featWT, bf16* linW2T, bf16* outWT)
{
    int id = blockIdx.x * 256 + threadIdx.x;
    if (id < 174080) {                       // vecB [1360][128]
        int r = id >> 7, c = id & 127;
        float v = (r < N04) ? v4[(size_t)r * 128 + c]
                : (r < N04 + N07) ? v7[(size_t)(r - N04) * 128 + c]
                : v8[(size_t)(r - N04 - N07) * 128 + c];
        vecB[id] = __float2bfloat16(v);
    } else if (id < 174080 + 98304) {        // W1T [3][256][128]
        int r = id - 174080; int z = r >> 15; int rem = r & 32767;
        int n = rem >> 7, k = rem & 127;
        const float* w = (z == 0) ? w1a : (z == 1) ? w1b : w1c;
        W1T[r] = __float2bfloat16(w[(size_t)k * 256 + n]);
    } else if (id < 272384 + 196608) {       // W2T [3][256][256]
        int r = id - 272384; int z = r >> 16; int rem = r & 65535;
        int n = rem >> 8, k = rem & 255;
        const float* w = (z == 0) ? w2a : (z == 1) ? w2b : w2c;
        W2T[r] = __float2bfloat16(w[(size_t)k * 256 + n]);
    } else if (id < 468992 + 65536) {        // featWT
        int r = id - 468992; int n = r >> 8, k = r & 255;
        featWT[r] = __float2bfloat16(featW[(size_t)k * 256 + n]);
    } else if (id < 534528 + 65536) {        // linW2T
        int r = id - 534528; int n = r >> 8, k = r & 255;
        linW2T[r] = __float2bfloat16(linW[(size_t)(256 + k) * 256 + n]);
    } else if (id < 600064 + 16384) {        // outWT [64][256], rows 12..63 zero
        int r = id - 600064; int p = r >> 8, k = r & 255;
        outWT[r] = __float2bfloat16((p < PRE) ? outW[(size_t)k * PRE + p] : 0.f);
    }
}
#define PREP_T_TOT (600064 + 16384)

// ---------------- 64x64-tile MFMA GEMM, runtime K (round-6 proven; extractors) ----------------
struct GemmZ {
    const unsigned short* A[3];
    const unsigned short* BT[3];
    int M[3]; int K[3]; int lda[3]; int ldb[3];
};

template <typename EP>
__global__ __launch_bounds__(256) void gemm_mfma64(GemmZ p, int Nv, EP ep)
{
    const int z = blockIdx.z;
    const int M = p.M[z], K = p.K[z], lda = p.lda[z], ldb = p.ldb[z];
    const int m0 = blockIdx.x * 64;
    const int n0 = blockIdx.y * 64;
    if (m0 >= M) return;
    __shared__ __align__(16) unsigned short As[64 * 72];
    __shared__ __align__(16) unsigned short Bs[64 * 72];
    const int t = threadIdx.x;
    const int srow  = t >> 2;
    const int skoff = (t & 3) * 16;
    const int lane = t & 63;
    const int w  = t >> 6;
    const int wm = (w & 1) * 32;
    const int wn = (w >> 1) * 32;
    const int l15 = lane & 15;
    const int l4  = lane >> 4;

    float4v acc[2][2];
#pragma unroll
    for (int i = 0; i < 2; ++i)
#pragma unroll
        for (int j = 0; j < 2; ++j) acc[i][j] = (float4v)(0.f);

    const int gm = m0 + srow;
    const bool avalid = (gm < M);
    const unsigned short* aptr = p.A[z]  + (size_t)gm * lda + skoff;
    const unsigned short* bptr = p.BT[z] + (size_t)(n0 + srow) * ldb + skoff;
    unsigned short* asw = &As[srow * 72 + skoff];
    unsigned short* bsw = &Bs[srow * 72 + skoff];
    const uint4 z4 = {0, 0, 0, 0};

    for (int kt = 0; kt < K; kt += 64) {
        uint4 av0 = avalid ? *(const uint4*)(aptr + kt)     : z4;
        uint4 av1 = avalid ? *(const uint4*)(aptr + kt + 8) : z4;
        uint4 bv0 = *(const uint4*)(bptr + kt);
        uint4 bv1 = *(const uint4*)(bptr + kt + 8);
        __syncthreads();
        *(uint4*)(asw)     = av0;
        *(uint4*)(asw + 8) = av1;
        *(uint4*)(bsw)     = bv0;
        *(uint4*)(bsw + 8) = bv1;
        __syncthreads();
#pragma unroll
        for (int ks = 0; ks < 2; ++ks) {
            short8 af[2], bq[2];
#pragma unroll
            for (int mi = 0; mi < 2; ++mi)
                af[mi] = *(const short8*)&As[(wm + mi * 16 + l15) * 72 + ks * 32 + l4 * 8];
#pragma unroll
            for (int ni = 0; ni < 2; ++ni)
                bq[ni] = *(const short8*)&Bs[(wn + ni * 16 + l15) * 72 + ks * 32 + l4 * 8];
#pragma unroll
            for (int mi = 0; mi < 2; ++mi)
#pragma unroll
                for (int ni = 0; ni < 2; ++ni)
                    acc[mi][ni] = __builtin_amdgcn_mfma_f32_16x16x32_bf16(af[mi], bq[ni], acc[mi][ni], 0, 0, 0);
        }
    }
#pragma unroll
    for (int mi = 0; mi < 2; ++mi) {
#pragma unroll
        for (int r = 0; r < 4; ++r) {
            int m = m0 + wm + mi * 16 + l4 * 4 + r;
            if (m >= M) continue;
#pragma unroll
            for (int ni = 0; ni < 2; ++ni) {
                int n = n0 + wn + ni * 16 + l15;
                if (n < Nv) ep(z, m, n, acc[mi][ni][r]);
            }
        }
    }
}

// ---------------- NEW: 64x256-block GEMM, K=256 fixed (GRU) ----------------
// 4 waves; wave w owns 64 rows x cols [w*64, w*64+64) = 4x4 MFMA tiles.
// Per k-iter per wave: 32 MFMA vs 16 ds_read_b128 (2x better ratio than gemm_mfma64).
template <typename EP>
__global__ __launch_bounds__(256) void gemm_w64(GemmZ p, int Nv, EP ep)
{
    const int z = blockIdx.z;
    const int M = p.M[z], lda = p.lda[z], ldb = p.ldb[z];
    const int m0 = blockIdx.x * 64;
    if (m0 >= M) return;
    const int n0 = blockIdx.y * 256;
    __shared__ __align__(16) unsigned short As[64 * 72];   // 9.2 KB
    __shared__ __align__(16) unsigned short Bs[256 * 72];  // 36.9 KB
    const int t = threadIdx.x;
    const int lane = t & 63;
    const int w = t >> 6;
    const int l15 = lane & 15, l4 = lane >> 4;
    const int srow = t >> 2, skoff = (t & 3) * 16;

    float4v acc[4][4];
#pragma unroll
    for (int i = 0; i < 4; ++i)
#pragma unroll
        for (int j = 0; j < 4; ++j) acc[i][j] = (float4v)(0.f);

    const int gm = m0 + srow;
    const bool avalid = (gm < M);
    const unsigned short* aptr = p.A[z] + (size_t)gm * lda + skoff;
    const unsigned short* bptr = p.BT[z] + (size_t)(n0 + t) * ldb;  // thread t stages n-row t
    const uint4 z4 = {0, 0, 0, 0};

    for (int kt = 0; kt < 256; kt += 64) {
        uint4 av0 = avalid ? *(const uint4*)(aptr + kt)     : z4;
        uint4 av1 = avalid ? *(const uint4*)(aptr + kt + 8) : z4;
        uint4 bv[8];
#pragma unroll
        for (int i = 0; i < 8; ++i) bv[i] = *(const uint4*)(bptr + kt + i * 8);
        __syncthreads();                      // previous iter's frag reads done
        *(uint4*)(&As[srow * 72 + skoff])     = av0;
        *(uint4*)(&As[srow * 72 + skoff + 8]) = av1;
#pragma unroll
        for (int i = 0; i < 8; ++i) *(uint4*)(&Bs[t * 72 + i * 8]) = bv[i];
        __syncthreads();
#pragma unroll
        for (int ks = 0; ks < 2; ++ks) {
            short8 af[4], bq[4];
#pragma unroll
            for (int mi = 0; mi < 4; ++mi)
                af[mi] = *(const short8*)&As[(mi * 16 + l15) * 72 + ks * 32 + l4 * 8];
#pragma unroll
            for (int ni = 0; ni < 4; ++ni)
                bq[ni] = *(const short8*)&Bs[(w * 64 + ni * 16 + l15) * 72 + ks * 32 + l4 * 8];
#pragma unroll
            for (int mi = 0; mi < 4; ++mi)
#pragma unroll
                for (int ni = 0; ni < 4; ++ni)
                    acc[mi][ni] = __builtin_amdgcn_mfma_f32_16x16x32_bf16(af[mi], bq[ni], acc[mi][ni], 0, 0, 0);
        }
    }
#pragma unroll
    for (int mi = 0; mi < 4; ++mi) {
#pragma unroll
        for (int r = 0; r < 4; ++r) {
            int m = m0 + mi * 16 + l4 * 4 + r;
            if (m >= M) continue;
#pragma unroll
            for (int ni = 0; ni < 4; ++ni) {
                int n = n0 + w * 64 + ni * 16 + l15;
                if (n < Nv) ep(z, m, n, acc[mi][ni][r]);
            }
        }
    }
}

// ---------------- epilogues ----------------
struct EPg1 {
    const float* b1[3]; float* h0F; bf16* h0T;
    __device__ void operator()(int z, int m, int n, float v) const {
        v += b1[z][n];
        int gr = c_Moff[z] + m;
        h0F[(size_t)gr * 256 + n] = v;
        h0T[(size_t)n * H0T_LD + c_Cb[z] + m] = __float2bfloat16(v);
    }
};
struct EPg2 {
    const float* deg; const float* h0F; float* h1F; const float* eps[3];
    __device__ void operator()(int z, int m, int n, float v) const {
        int gr = c_Moff[z] + m;
        h1F[(size_t)gr * 256 + n] = v / deg[gr] + eps[z][0] * h0F[(size_t)gr * 256 + n];
    }
};
struct EPg3 {
    const float* b2[3]; void* outbase; size_t ooff[3]; const int* flag; bf16* f4B;
    __device__ void operator()(int z, int m, int n, float v) const {
        v += b2[z][n];
        size_t i = ooff[z] + (size_t)m * 256 + n;
        if (*flag) ((bf16*)outbase)[i] = __float2bfloat16(v);
        else       ((float*)outbase)[i] = v;
        if (z == 0) f4B[(size_t)m * 256 + n] = __float2bfloat16(v);
    }
};
struct EPfp2a {
    const float* sb; bf16* fpreB;
    __device__ void operator()(int z, int m, int n, float v) const {
        fpreB[(size_t)m * 256 + n] = __float2bfloat16(v + sb[0]);
    }
};
struct EPfp2b {
    float* fp2;
    __device__ void operator()(int z, int m, int n, float v) const {
        fp2[(size_t)m * 256 + n] = v;
    }
};
struct EPpred {
    const float* ob; void* outbase; const int* flag;
    __device__ void operator()(int z, int m, int n, float v) const {
        v += ob[n];
        size_t i = (size_t)m * PRE + n;
        if (*flag) ((bf16*)outbase)[i] = __float2bfloat16(v);
        else       ((float*)outbase)[i] = v;
    }
};
struct EPgates3 {
    bf16* rh; bf16* ub; const bf16* hB;
    const float* b1; const float* w1r0; const float* feat; int s;
    __device__ void operator()(int z, int m, int n, float v) const {
        int b = m / N04, nn = m - b * N04;
        float x = feat[((size_t)b * S_ + s) * N04 + nn];
        float g = fsigmoid(v + b1[n] + x * w1r0[n]);
        int p = nn * 512 + n;
        int base = b * UOFF;
        if (p < UOFF) {
            int idx = base + p;
            rh[idx] = __float2bfloat16(g * __bfloat162float(hB[idx]));
        } else {
            ub[base + (p - UOFF)] = __float2bfloat16(g);
        }
    }
};
struct EPcand3 {
    bf16* uhc; const bf16* ub; const bf16* hB;
    const float* b2; const float* w2r0; const float* feat; int s;
    __device__ void operator()(int z, int m, int n, float v) const {
        int b = m / N04, nn = m - b * N04;
        float x = feat[((size_t)b * S_ + s) * N04 + nn];
        float c = ftanh(v + b2[n] + x * w2r0[n]);
        size_t idx = (size_t)m * 256 + n;
        float u = __bfloat162float(ub[idx]);
        float h = __bfloat162float(hB[idx]);
        uhc[idx] = __float2bfloat16(u * h + (1.f - u) * c);
    }
};
struct EPlin3 {
    bf16* hB; const float* lb; const float* fp2;
    __device__ void operator()(int z, int m, int n, float v) const {
        int nn = m % N04;
        hB[(size_t)m * 256 + n] = __float2bfloat16(v + lb[n] + fp2[(size_t)nn * 256 + n]);
    }
};

// ---------------- merged small kernels ----------------
__global__ void deg_all(const float* a4, const float* a7, const float* a8, float* deg)
{
    int z = blockIdx.z;
    int Mi = c_Mi[z];
    int row = blockIdx.x;
    if (row >= Mi) return;
    const float* adj = (z == 0) ? a4 : (z == 1) ? a7 : a8;
    float s = 0.f;
    for (int j = threadIdx.x; j < Mi; j += 64) s += adj[(size_t)row * Mi + j];
#pragma unroll
    for (int off = 32; off > 0; off >>= 1) s += __shfl_down(s, off, 64);
    if (threadIdx.x == 0) deg[c_Moff[z] + row] = s;
}

__global__ __launch_bounds__(256) void stats_all(const float* h1F, float* mu, float* rstd)
{
    int z = blockIdx.z;
    int Mi = c_Mi[z], moff = c_Moff[z];
    int j = blockIdx.x;
    int t = threadIdx.x;
    float s = 0.f, ss = 0.f;
    for (int i = t; i < Mi; i += 256) {
        float v = h1F[(size_t)(moff + i) * 256 + j];
        s += v; ss += v * v;
    }
    __shared__ float sh[256], sh2[256];
    sh[t] = s; sh2[t] = ss;
    __syncthreads();
    for (int off = 128; off > 0; off >>= 1) {
        if (t < off) { sh[t] += sh[t + off]; sh2[t] += sh2[t + off]; }
        __syncthreads();
    }
    if (t == 0) {
        float m = sh[0] / (float)Mi;
        float var = sh2[0] / (float)Mi - m * m;
        mu[z * 256 + j] = m;
        rstd[z * 256 + j] = rsqrtf(var + 1e-5f);
    }
}

__global__ __launch_bounds__(256) void norm_all(const float* h1F, const float* mu, const float* rstd,
                                                const float* ga, const float* gb, const float* gc,
                                                const float* ba, const float* bb, const float* bc,
                                                bf16* nh1B)
{
    int r = blockIdx.x;
    int n = threadIdx.x;
    int z = (r < N04) ? 0 : (r < N04 + N07) ? 1 : 2;
    const float* g  = (z == 0) ? ga : (z == 1) ? gb : gc;
    const float* bt = (z == 0) ? ba : (z == 1) ? bb : bc;
    float v = (h1F[(size_t)r * 256 + n] - mu[z * 256 + n]) * rstd[z * 256 + n] * g[n] + bt[n];
    nh1B[(size_t)r * 256 + n] = __float2bfloat16(v);
}

extern "C" void kernel_launch(void* const* d_in, const int* in_sizes, int n_in,
                              void* d_out, int out_size, void* d_ws, size_t ws_size,
                              hipStream_t stream)
{
    char* wp = (char*)d_ws;
    auto carve = [&](size_t bytes) -> void* {
        void* p = (void*)wp;
        wp += (bytes + 255) & ~(size_t)255;
        return p;
    };
    float* arena = (float*)carve((size_t)g_tbl.off[NT] * 4);
    int*   flag  = (int*)carve(256);
    bf16*  hb_a  = (bf16*)carve((size_t)BN * HID * 2);
    bf16*  hb_b  = (bf16*)carve((size_t)BN * HID * 2);
    bf16*  rh    = (bf16*)carve((size_t)BN * HID * 2);
    bf16*  uhc   = (bf16*)carve((size_t)BN * HID * 2);
    bf16*  ubufB = (bf16*)carve((size_t)BN * HID * 2);
    bf16*  WgT   = (bf16*)carve((size_t)512 * 256 * 2);
    bf16*  WcT   = (bf16*)carve((size_t)256 * 256 * 2);
    bf16*  WlT   = (bf16*)carve((size_t)256 * 256 * 2);
    bf16*  vecB  = (bf16*)carve((size_t)MTOT * 128 * 2);
    bf16*  adjB  = (bf16*)carve((size_t)(N04 * 320 + N07 * 896 + N08 * 192) * 2);
    bf16*  W1T   = (bf16*)carve((size_t)3 * 256 * 128 * 2);
    bf16*  W2T   = (bf16*)carve((size_t)3 * 256 * 256 * 2);
    bf16*  featWT= (bf16*)carve((size_t)256 * 256 * 2);
    bf16*  linW2T= (bf16*)carve((size_t)256 * 256 * 2);
    bf16*  outWT = (bf16*)carve((size_t)64 * 256 * 2);
    float* h0F   = (float*)carve((size_t)MTOT * 256 * 4);
    bf16*  h0T   = (bf16*)carve((size_t)256 * H0T_LD * 2);
    float* h1F   = (float*)carve((size_t)MTOT * 256 * 4);
    bf16*  nh1B  = (bf16*)carve((size_t)MTOT * 256 * 2);
    float* degb  = (float*)carve((size_t)MTOT * 4);
    float* mub   = (float*)carve(3 * 256 * 4);
    float* rstdb = (float*)carve(3 * 256 * 4);
    bf16*  f4B   = (bf16*)carve((size_t)N04 * 256 * 2);
    bf16*  fpreB = (bf16*)carve((size_t)N04 * 256 * 2);
    float* fp2   = (float*)carve((size_t)N04 * 256 * 4);

    // --- dtype sniff + canonical fp32 conversion ---
    sniff_kernel<<<1, 256, 0, stream>>>((const unsigned short*)d_in[0], flag);
    Ptrs ptrs;
    for (int i = 0; i < NT; ++i) ptrs.p[i] = d_in[i];
    convert_all<<<g_tbl.blk[NT], 256, 0, stream>>>(ptrs, arena, flag);

    auto A = [&](int i) -> const float* { return arena + g_tbl.off[i]; };

    // --- operand prep ---
    prep_weights<<<1024, 256, 0, stream>>>(A(28), A(30), A(34), WgT, WcT, WlT);
    prep_adjB<<<dim3(N07, 1, 3), 256, 0, stream>>>(A(4), A(5), A(6), adjB);
    prep_transposes<<<(PREP_T_TOT + 255) / 256, 256, 0, stream>>>(
        A(0), A(1), A(2), A(7), A(14), A(21), A(9), A(16), A(23),
        A(32), A(34), A(36), vecB, W1T, W2T, featWT, linW2T, outWT);

    hipMemsetAsync(hb_a, 0, (size_t)BN * HID * 2, stream);
    hipMemsetAsync(h0T, 0, (size_t)256 * H0T_LD * 2, stream);

    const size_t o_f4 = (size_t)B_ * N04 * PRE;
    const size_t o_f7 = o_f4 + (size_t)N04 * ENC;
    const size_t o_f8 = o_f7 + (size_t)N07 * ENC;

    // --- deg ---
    deg_all<<<dim3(N07, 1, 3), 64, 0, stream>>>(A(4), A(5), A(6), degb);

    // --- E1: h0 = vec@W1 + b1 ---
    {
        GemmZ p;
        for (int z = 0; z < 3; ++z) {
            p.A[z] = (const unsigned short*)(vecB + (size_t)c_Moff[z] * 128);
            p.BT[z] = (const unsigned short*)(W1T + (size_t)z * 256 * 128);
            p.M[z] = c_Mi[z]; p.K[z] = 128; p.lda[z] = 128; p.ldb[z] = 128;
        }
        EPg1 ep{{A(8), A(15), A(22)}, h0F, h0T};
        gemm_mfma64<<<dim3(14, 4, 3), 256, 0, stream>>>(p, 256, ep);
    }
    // --- E2: h1 = (adj@h0)/deg + eps*h0 ---
    {
        GemmZ p;
        for (int z = 0; z < 3; ++z) {
            p.A[z] = (const unsigned short*)(adjB + c_Aoff[z]);
            p.BT[z] = (const unsigned short*)(h0T + c_Cb[z]);
            p.M[z] = c_Mi[z]; p.K[z] = c_Kp[z]; p.lda[z] = c_Kp[z]; p.ldb[z] = H0T_LD;
        }
        EPg2 ep{degb, h0F, h1F, {A(13), A(20), A(27)}};
        gemm_mfma64<<<dim3(14, 4, 3), 256, 0, stream>>>(p, 256, ep);
    }
    // --- BN stats + normalize ---
    stats_all<<<dim3(256, 1, 3), 256, 0, stream>>>(h1F, mub, rstdb);
    norm_all<<<MTOT, 256, 0, stream>>>(h1F, mub, rstdb, A(11), A(18), A(25), A(12), A(19), A(26), nh1B);
    // --- E3: f = nh1@W2 + b2 ---
    {
        GemmZ p;
        for (int z = 0; z < 3; ++z) {
            p.A[z] = (const unsigned short*)(nh1B + (size_t)c_Moff[z] * 256);
            p.BT[z] = (const unsigned short*)(W2T + (size_t)z * 256 * 256);
            p.M[z] = c_Mi[z]; p.K[z] = 256; p.lda[z] = 256; p.ldb[z] = 256;
        }
        EPg3 ep{{A(10), A(17), A(24)}, d_out, {o_f4, o_f7, o_f8}, flag, f4B};
        gemm_mfma64<<<dim3(14, 4, 3), 256, 0, stream>>>(p, 256, ep);
    }
    // --- fp2 = (f4@featW + featb) @ linW[256:512] ---
    {
        GemmZ p{};
        p.A[0] = (const unsigned short*)f4B; p.BT[0] = (const unsigned short*)featWT;
        p.M[0] = N04; p.K[0] = 256; p.lda[0] = 256; p.ldb[0] = 256;
        gemm_mfma64<<<dim3(5, 4, 1), 256, 0, stream>>>(p, 256, EPfp2a{A(33), fpreB});
        p.A[0] = (const unsigned short*)fpreB; p.BT[0] = (const unsigned short*)linW2T;
        gemm_mfma64<<<dim3(5, 4, 1), 256, 0, stream>>>(p, 256, EPfp2b{fp2});
    }

    // --- GRU scan: 64x256-block kernel, all-bf16 state ---
    const float* feat = A(3);
    bf16* hcB = hb_a;
    bf16* hnB = hb_b;
    for (int s = 0; s < S_; ++s) {
        GemmZ p{};
        p.M[0] = BN; p.K[0] = 256; p.lda[0] = 256; p.ldb[0] = 256;
        p.A[0] = (const unsigned short*)hcB; p.BT[0] = (const unsigned short*)WgT;
        gemm_w64<<<dim3(BN / 64, 2, 1), 256, 0, stream>>>(p, 512,
            EPgates3{rh, ubufB, hcB, A(29), A(28), feat, s});
        p.A[0] = (const unsigned short*)rh; p.BT[0] = (const unsigned short*)WcT;
        gemm_w64<<<dim3(BN / 64, 1, 1), 256, 0, stream>>>(p, 256,
            EPcand3{uhc, ubufB, hcB, A(31), A(30), feat, s});
        p.A[0] = (const unsigned short*)uhc; p.BT[0] = (const unsigned short*)WlT;
        gemm_w64<<<dim3(BN / 64, 1, 1), 256, 0, stream>>>(p, 256,
            EPlin3{hnB, A(35), fp2});
        bf16* tb = hcB; hcB = hnB; hnB = tb;
    }

    // --- pred = h@outW + outb (64-tile kernel, N padded to 64, guard n<12) ---
    {
        GemmZ p{};
        p.A[0] = (const unsigned short*)hcB; p.BT[0] = (const unsigned short*)outWT;
        p.M[0] = BN; p.K[0] = 256; p.lda[0] = 256; p.ldb[0] = 256;
        gemm_mfma64<<<dim3(BN / 64, 1, 1), 256, 0, stream>>>(p, PRE, EPpred{A(37), d_out, flag});
    }
}

// Round 10
// 1104.196 us; speedup vs baseline: 7.0548x; 1.9432x over previous
//
#include <hip/hip_runtime.h>
#include <hip/hip_bf16.h>
#include <math.h>

using bf16 = __hip_bfloat16;
using short8  = __attribute__((ext_vector_type(8))) short;
using float4v = __attribute__((ext_vector_type(4))) float;

#define B_   64
#define S_   12
#define N04  307
#define N07  883
#define N08  170
#define BN   (B_ * N04)        // 19648 = 307*64 (exact multiple of 64)
#define HID  256
#define ENC  256
#define PRE  12
#define UOFF (N04 * HID)       // 78592 flat split point

// extractor geometry (plain constexpr — host reads these; __constant__ host shadow is zero-init)
constexpr int c_Mi[3]   = {N04, N07, N08};
constexpr int c_Kp[3]   = {320, 896, 192};
constexpr int c_Moff[3] = {0, N04, N04 + N07};
constexpr int c_Aoff[3] = {0, N04 * 320, N04 * 320 + N07 * 896};
constexpr int c_Cb[3]   = {0, 320, 320 + 896};
#define MTOT  (N04 + N07 + N08)   // 1360
#define H0T_LD 1408

// ---------------- static tensor tables ----------------
#define NT 38
constexpr int g_sz[NT] = {
    39296, 113024, 21760, 235776, 94249, 779689, 28900,
    32768, 256, 65536, 256, 256, 256, 1,
    32768, 256, 65536, 256, 256, 256, 1,
    32768, 256, 65536, 256, 256, 256, 1,
    131584, 512, 65792, 256, 65536, 1, 131072, 256, 3072, 12
};
struct Tables { int off[NT + 1]; int blk[NT + 1]; };
constexpr Tables mk_tables() {
    Tables t{};
    t.off[0] = 0; t.blk[0] = 0;
    for (int i = 0; i < NT; ++i) {
        t.off[i + 1] = t.off[i] + g_sz[i];
        t.blk[i + 1] = t.blk[i] + (g_sz[i] + 1023) / 1024;
    }
    return t;
}
constexpr Tables g_tbl = mk_tables();

static __device__ __forceinline__ float fsigmoid(float t) {
    return __builtin_amdgcn_rcpf(1.f + __expf(-t));
}
static __device__ __forceinline__ float ftanh(float t) {
    return 1.f - 2.f * __builtin_amdgcn_rcpf(__expf(2.f * t) + 1.f);
}

// MFMA B-fragment swizzle: (n,k) of BT[N][K] -> frag[ntile*KT+ktile][lane][8]
// (layout correctness verified in rounds 7/8 — both passed with this mapping)
static __device__ __forceinline__ int frag_idx(int n, int k, int K) {
    return (((n >> 4) * (K >> 5) + (k >> 5)) << 9) + (((k >> 3) & 3) << 7) + ((n & 15) << 3) + (k & 7);
}

// ---------------- dtype sniffer ----------------
__global__ void sniff_kernel(const unsigned short* raw, int* flag)
{
    __shared__ int sh[256];
    int t = threadIdx.x, cnt = 0;
    for (int i = t; i < 2048; i += 256) {
        unsigned int w = ((unsigned int)raw[i]) << 16;
        float a = fabsf(__uint_as_float(w));
        if (a > 1e-3f && a < 100.f) cnt++;
    }
    sh[t] = cnt; __syncthreads();
    for (int off = 128; off > 0; off >>= 1) {
        if (t < off) sh[t] += sh[t + off];
        __syncthreads();
    }
    if (t == 0) *flag = (sh[0] > 1536) ? 1 : 0;
}

struct Ptrs { const void* p[NT]; };

__global__ __launch_bounds__(256) void convert_all(Ptrs a, float* arena, const int* flag)
{
    const int bf = *flag;
    int b = blockIdx.x;
    int t = 0;
    while (b >= g_tbl.blk[t + 1]) ++t;
    const int base = (b - g_tbl.blk[t]) * 1024;
    const int n = g_sz[t];
    const void* src = a.p[t];
    float* dst = arena + g_tbl.off[t];
#pragma unroll
    for (int k = 0; k < 4; ++k) {
        int j = base + k * 256 + threadIdx.x;
        if (j < n)
            dst[j] = bf ? __bfloat162float(((const bf16*)src)[j]) : ((const float*)src)[j];
    }
}

// ---------------- GRU weights in frag order ----------------
__global__ __launch_bounds__(256) void prep_weights(const float* w1, const float* w2, const float* wl,
                                                    bf16* WgT, bf16* WcT, bf16* WlT)
{
    int id = blockIdx.x * 256 + threadIdx.x;
    if (id < 131072) {                       // Wg: N=512,K=256; BT[n][k]=w1[1+k][n]
        int n = id >> 8, k = id & 255;
        WgT[frag_idx(n, k, 256)] = __float2bfloat16(w1[(size_t)(1 + k) * 512 + n]);
    } else if (id < 196608) {                // Wc
        int r = id - 131072; int n = r >> 8, k = r & 255;
        WcT[frag_idx(n, k, 256)] = __float2bfloat16(w2[(size_t)(1 + k) * 256 + n]);
    } else if (id < 262144) {                // Wl[:256]
        int r = id - 196608; int n = r >> 8, k = r & 255;
        WlT[frag_idx(n, k, 256)] = __float2bfloat16(wl[(size_t)k * 256 + n]);
    }
}

// ---------------- extractor operand prep (round-6 proven) ----------------
__global__ __launch_bounds__(256) void prep_adjB(const float* a4, const float* a7, const float* a8, bf16* adjB)
{
    int z = blockIdx.z;
    int Mi = c_Mi[z], Kp = c_Kp[z];
    int m = blockIdx.x;
    if (m >= Mi) return;
    const float* src = (z == 0) ? a4 : (z == 1) ? a7 : a8;
    bf16* dst = adjB + c_Aoff[z] + (size_t)m * Kp;
    for (int c = threadIdx.x; c < Kp; c += 256)
        dst[c] = (c < Mi) ? __float2bfloat16(src[(size_t)m * Mi + c]) : __float2bfloat16(0.f);
}

__global__ __launch_bounds__(256) void prep_transposes(
    const float* v4, const float* v7, const float* v8,
    const float* w1a, const float* w1b, const float* w1c,
    const float* w2a, const float* w2b, const float* w2c,
    const float* featW, const float* linW, const float* outW,
    bf16* vecB, bf16* W1T, bf16* W2T, bf16* featWT, bf16* linW2T, bf16* outWT)
{
    int id = blockIdx.x * 256 + threadIdx.x;
    if (id < 174080) {                       // vecB [1360][128]
        int r = id >> 7, c = id & 127;
        float v = (r < N04) ? v4[(size_t)r * 128 + c]
                : (r < N04 + N07) ? v7[(size_t)(r - N04) * 128 + c]
                : v8[(size_t)(r - N04 - N07) * 128 + c];
        vecB[id] = __float2bfloat16(v);
    } else if (id < 174080 + 98304) {        // W1T [3][256][128]
        int r = id - 174080; int z = r >> 15; int rem = r & 32767;
        int n = rem >> 7, k = rem & 127;
        const float* w = (z == 0) ? w1a : (z == 1) ? w1b : w1c;
        W1T[r] = __float2bfloat16(w[(size_t)k * 256 + n]);
    } else if (id < 272384 + 196608) {       // W2T [3][256][256]
        int r = id - 272384; int z = r >> 16; int rem = r & 65535;
        int n = rem >> 8, k = rem & 255;
        const float* w = (z == 0) ? w2a : (z == 1) ? w2b : w2c;
        W2T[r] = __float2bfloat16(w[(size_t)k * 256 + n]);
    } else if (id < 468992 + 65536) {        // featWT
        int r = id - 468992; int n = r >> 8, k = r & 255;
        featWT[r] = __float2bfloat16(featW[(size_t)k * 256 + n]);
    } else if (id < 534528 + 65536) {        // linW2T
        int r = id - 534528; int n = r >> 8, k = r & 255;
        linW2T[r] = __float2bfloat16(linW[(size_t)(256 + k) * 256 + n]);
    } else if (id < 600064 + 16384) {        // outWT [64][256], rows 12..63 zero
        int r = id - 600064; int p = r >> 8, k = r & 255;
        outWT[r] = __float2bfloat16((p < PRE) ? outW[(size_t)k * PRE + p] : 0.f);
    }
}
#define PREP_T_TOT (600064 + 16384)

// ---------------- 64x64-tile MFMA GEMM, runtime K (round-6 proven; extractors/pred) ----------------
struct GemmZ {
    const unsigned short* A[3];
    const unsigned short* BT[3];
    int M[3]; int K[3]; int lda[3]; int ldb[3];
};

template <typename EP>
__global__ __launch_bounds__(256) void gemm_mfma64(GemmZ p, int Nv, EP ep)
{
    const int z = blockIdx.z;
    const int M = p.M[z], K = p.K[z], lda = p.lda[z], ldb = p.ldb[z];
    const int m0 = blockIdx.x * 64;
    const int n0 = blockIdx.y * 64;
    if (m0 >= M) return;
    __shared__ __align__(16) unsigned short As[64 * 72];
    __shared__ __align__(16) unsigned short Bs[64 * 72];
    const int t = threadIdx.x;
    const int srow  = t >> 2;
    const int skoff = (t & 3) * 16;
    const int lane = t & 63;
    const int w  = t >> 6;
    const int wm = (w & 1) * 32;
    const int wn = (w >> 1) * 32;
    const int l15 = lane & 15;
    const int l4  = lane >> 4;

    float4v acc[2][2];
#pragma unroll
    for (int i = 0; i < 2; ++i)
#pragma unroll
        for (int j = 0; j < 2; ++j) acc[i][j] = (float4v)(0.f);

    const int gm = m0 + srow;
    const bool avalid = (gm < M);
    const unsigned short* aptr = p.A[z]  + (size_t)gm * lda + skoff;
    const unsigned short* bptr = p.BT[z] + (size_t)(n0 + srow) * ldb + skoff;
    unsigned short* asw = &As[srow * 72 + skoff];
    unsigned short* bsw = &Bs[srow * 72 + skoff];
    const uint4 z4 = {0, 0, 0, 0};

    for (int kt = 0; kt < K; kt += 64) {
        uint4 av0 = avalid ? *(const uint4*)(aptr + kt)     : z4;
        uint4 av1 = avalid ? *(const uint4*)(aptr + kt + 8) : z4;
        uint4 bv0 = *(const uint4*)(bptr + kt);
        uint4 bv1 = *(const uint4*)(bptr + kt + 8);
        __syncthreads();
        *(uint4*)(asw)     = av0;
        *(uint4*)(asw + 8) = av1;
        *(uint4*)(bsw)     = bv0;
        *(uint4*)(bsw + 8) = bv1;
        __syncthreads();
#pragma unroll
        for (int ks = 0; ks < 2; ++ks) {
            short8 af[2], bq[2];
#pragma unroll
            for (int mi = 0; mi < 2; ++mi)
                af[mi] = *(const short8*)&As[(wm + mi * 16 + l15) * 72 + ks * 32 + l4 * 8];
#pragma unroll
            for (int ni = 0; ni < 2; ++ni)
                bq[ni] = *(const short8*)&Bs[(wn + ni * 16 + l15) * 72 + ks * 32 + l4 * 8];
#pragma unroll
            for (int mi = 0; mi < 2; ++mi)
#pragma unroll
                for (int ni = 0; ni < 2; ++ni)
                    acc[mi][ni] = __builtin_amdgcn_mfma_f32_16x16x32_bf16(af[mi], bq[ni], acc[mi][ni], 0, 0, 0);
        }
    }
#pragma unroll
    for (int mi = 0; mi < 2; ++mi) {
#pragma unroll
        for (int r = 0; r < 4; ++r) {
            int m = m0 + wm + mi * 16 + l4 * 4 + r;
            if (m >= M) continue;
#pragma unroll
            for (int ni = 0; ni < 2; ++ni) {
                int n = n0 + wn + ni * 16 + l15;
                if (n < Nv) ep(z, m, n, acc[mi][ni][r]);
            }
        }
    }
}

// ---------------- NEW GRU GEMM: 64x128 block, K=256, B-frags in registers ----------------
// Wave w: 64 rows x cols [n0 + w*32, +32) = 4 m-tiles x 2 n-tiles.
// B loaded once (16 coalesced 1KB frag reads, L2-hot); A staged full-K in LDS, ONE barrier.
// Per k-tile per wave: 4 ds_read_b128 + 8 MFMA (2:1) — vs round-6's 1:1 with 8 barriers.
// M must be a multiple of 64 (true for BN).
template <typename EP>
__global__ __launch_bounds__(256) void gemm_rb(const unsigned short* __restrict__ Aq,
                                               const unsigned short* __restrict__ Bf,
                                               int Nv, EP ep)
{
    __shared__ __align__(16) unsigned short As[64 * 264];   // 33.8 KB, stride 264 shorts
    const int m0 = blockIdx.x * 64;
    const int n0 = blockIdx.y * 128;
    const int t = threadIdx.x;
    const int lane = t & 63;
    const int w = t >> 6;
    const int l15 = lane & 15, l4 = lane >> 4;

    // B-fragments for this wave's 2 n-tiles x 8 k-tiles (issued first, in flight during A staging)
    const int nt0 = (n0 >> 4) + w * 2;
    short8 bq[2][8];
#pragma unroll
    for (int ni = 0; ni < 2; ++ni)
#pragma unroll
        for (int kt = 0; kt < 8; ++kt)
            bq[ni][kt] = *(const short8*)(Bf + (((size_t)((nt0 + ni) * 8 + kt)) << 9) + lane * 8);

    // stage A rows [m0, m0+64) x 256 shorts — 32 consecutive threads cover one row (coalesced 512B)
#pragma unroll
    for (int p = 0; p < 8; ++p) {
        int u = p * 256 + t;
        int r = u >> 5, c = u & 31;
        uint4 v = *(const uint4*)(Aq + (size_t)(m0 + r) * 256 + c * 8);
        *(uint4*)(&As[r * 264 + c * 8]) = v;
    }
    __syncthreads();

    float4v acc[4][2];
#pragma unroll
    for (int i = 0; i < 4; ++i)
#pragma unroll
        for (int j = 0; j < 2; ++j) acc[i][j] = (float4v)(0.f);

#pragma unroll
    for (int kt = 0; kt < 8; ++kt) {
        short8 a[4];
#pragma unroll
        for (int mi = 0; mi < 4; ++mi)
            a[mi] = *(const short8*)&As[(mi * 16 + l15) * 264 + kt * 32 + l4 * 8];
#pragma unroll
        for (int mi = 0; mi < 4; ++mi) {
            acc[mi][0] = __builtin_amdgcn_mfma_f32_16x16x32_bf16(a[mi], bq[0][kt], acc[mi][0], 0, 0, 0);
            acc[mi][1] = __builtin_amdgcn_mfma_f32_16x16x32_bf16(a[mi], bq[1][kt], acc[mi][1], 0, 0, 0);
        }
    }
#pragma unroll
    for (int mi = 0; mi < 4; ++mi) {
#pragma unroll
        for (int r = 0; r < 4; ++r) {
            int m = m0 + mi * 16 + l4 * 4 + r;
#pragma unroll
            for (int ni = 0; ni < 2; ++ni) {
                int n = n0 + w * 32 + ni * 16 + l15;
                if (n < Nv) ep(0, m, n, acc[mi][ni][r]);
            }
        }
    }
}

// ---------------- epilogues ----------------
struct EPg1 {
    const float* b1[3]; float* h0F; bf16* h0T;
    __device__ void operator()(int z, int m, int n, float v) const {
        v += b1[z][n];
        int gr = c_Moff[z] + m;
        h0F[(size_t)gr * 256 + n] = v;
        h0T[(size_t)n * H0T_LD + c_Cb[z] + m] = __float2bfloat16(v);
    }
};
struct EPg2 {
    const float* deg; const float* h0F; float* h1F; const float* eps[3];
    __device__ void operator()(int z, int m, int n, float v) const {
        int gr = c_Moff[z] + m;
        h1F[(size_t)gr * 256 + n] = v / deg[gr] + eps[z][0] * h0F[(size_t)gr * 256 + n];
    }
};
struct EPg3 {
    const float* b2[3]; void* outbase; size_t ooff[3]; const int* flag; bf16* f4B;
    __device__ void operator()(int z, int m, int n, float v) const {
        v += b2[z][n];
        size_t i = ooff[z] + (size_t)m * 256 + n;
        if (*flag) ((bf16*)outbase)[i] = __float2bfloat16(v);
        else       ((float*)outbase)[i] = v;
        if (z == 0) f4B[(size_t)m * 256 + n] = __float2bfloat16(v);
    }
};
struct EPfp2a {
    const float* sb; bf16* fpreB;
    __device__ void operator()(int z, int m, int n, float v) const {
        fpreB[(size_t)m * 256 + n] = __float2bfloat16(v + sb[0]);
    }
};
struct EPfp2b {
    float* fp2;
    __device__ void operator()(int z, int m, int n, float v) const {
        fp2[(size_t)m * 256 + n] = v;
    }
};
struct EPpred {
    const float* ob; void* outbase; const int* flag;
    __device__ void operator()(int z, int m, int n, float v) const {
        v += ob[n];
        size_t i = (size_t)m * PRE + n;
        if (*flag) ((bf16*)outbase)[i] = __float2bfloat16(v);
        else       ((float*)outbase)[i] = v;
    }
};
struct EPgates3 {
    bf16* rh; bf16* ub; const bf16* hB;
    const float* b1; const float* w1r0; const float* feat; int s;
    __device__ void operator()(int z, int m, int n, float v) const {
        int b = m / N04, nn = m - b * N04;
        float x = feat[((size_t)b * S_ + s) * N04 + nn];
        float g = fsigmoid(v + b1[n] + x * w1r0[n]);
        int p = nn * 512 + n;
        int base = b * UOFF;
        if (p < UOFF) {
            int idx = base + p;
            rh[idx] = __float2bfloat16(g * __bfloat162float(hB[idx]));
        } else {
            ub[base + (p - UOFF)] = __float2bfloat16(g);
        }
    }
};
struct EPcand3 {
    bf16* uhc; const bf16* ub; const bf16* hB;
    const float* b2; const float* w2r0; const float* feat; int s;
    __device__ void operator()(int z, int m, int n, float v) const {
        int b = m / N04, nn = m - b * N04;
        float x = feat[((size_t)b * S_ + s) * N04 + nn];
        float c = ftanh(v + b2[n] + x * w2r0[n]);
        size_t idx = (size_t)m * 256 + n;
        float u = __bfloat162float(ub[idx]);
        float h = __bfloat162float(hB[idx]);
        uhc[idx] = __float2bfloat16(u * h + (1.f - u) * c);
    }
};
struct EPlin3 {
    bf16* hB; const float* lb; const float* fp2;
    __device__ void operator()(int z, int m, int n, float v) const {
        int nn = m % N04;
        hB[(size_t)m * 256 + n] = __float2bfloat16(v + lb[n] + fp2[(size_t)nn * 256 + n]);
    }
};

// ---------------- merged small kernels ----------------
__global__ void deg_all(const float* a4, const float* a7, const float* a8, float* deg)
{
    int z = blockIdx.z;
    int Mi = c_Mi[z];
    int row = blockIdx.x;
    if (row >= Mi) return;
    const float* adj = (z == 0) ? a4 : (z == 1) ? a7 : a8;
    float s = 0.f;
    for (int j = threadIdx.x; j < Mi; j += 64) s += adj[(size_t)row * Mi + j];
#pragma unroll
    for (int off = 32; off > 0; off >>= 1) s += __shfl_down(s, off, 64);
    if (threadIdx.x == 0) deg[c_Moff[z] + row] = s;
}

__global__ __launch_bounds__(256) void stats_all(const float* h1F, float* mu, float* rstd)
{
    int z = blockIdx.z;
    int Mi = c_Mi[z], moff = c_Moff[z];
    int j = blockIdx.x;
    int t = threadIdx.x;
    float s = 0.f, ss = 0.f;
    for (int i = t; i < Mi; i += 256) {
        float v = h1F[(size_t)(moff + i) * 256 + j];
        s += v; ss += v * v;
    }
    __shared__ float sh[256], sh2[256];
    sh[t] = s; sh2[t] = ss;
    __syncthreads();
    for (int off = 128; off > 0; off >>= 1) {
        if (t < off) { sh[t] += sh[t + off]; sh2[t] += sh2[t + off]; }
        __syncthreads();
    }
    if (t == 0) {
        float m = sh[0] / (float)Mi;
        float var = sh2[0] / (float)Mi - m * m;
        mu[z * 256 + j] = m;
        rstd[z * 256 + j] = rsqrtf(var + 1e-5f);
    }
}

__global__ __launch_bounds__(256) void norm_all(const float* h1F, const float* mu, const float* rstd,
                                                const float* ga, const float* gb, const float* gc,
                                                const float* ba, const float* bb, const float* bc,
                                                bf16* nh1B)
{
    int r = blockIdx.x;
    int n = threadIdx.x;
    int z = (r < N04) ? 0 : (r < N04 + N07) ? 1 : 2;
    const float* g  = (z == 0) ? ga : (z == 1) ? gb : gc;
    const float* bt = (z == 0) ? ba : (z == 1) ? bb : bc;
    float v = (h1F[(size_t)r * 256 + n] - mu[z * 256 + n]) * rstd[z * 256 + n] * g[n] + bt[n];
    nh1B[(size_t)r * 256 + n] = __float2bfloat16(v);
}

extern "C" void kernel_launch(void* const* d_in, const int* in_sizes, int n_in,
                              void* d_out, int out_size, void* d_ws, size_t ws_size,
                              hipStream_t stream)
{
    char* wp = (char*)d_ws;
    auto carve = [&](size_t bytes) -> void* {
        void* p = (void*)wp;
        wp += (bytes + 255) & ~(size_t)255;
        return p;
    };
    float* arena = (float*)carve((size_t)g_tbl.off[NT] * 4);
    int*   flag  = (int*)carve(256);
    bf16*  hb_a  = (bf16*)carve((size_t)BN * HID * 2);
    bf16*  hb_b  = (bf16*)carve((size_t)BN * HID * 2);
    bf16*  rh    = (bf16*)carve((size_t)BN * HID * 2);
    bf16*  uhc   = (bf16*)carve((size_t)BN * HID * 2);
    bf16*  ubufB = (bf16*)carve((size_t)BN * HID * 2);
    bf16*  WgT   = (bf16*)carve((size_t)512 * 256 * 2);
    bf16*  WcT   = (bf16*)carve((size_t)256 * 256 * 2);
    bf16*  WlT   = (bf16*)carve((size_t)256 * 256 * 2);
    bf16*  vecB  = (bf16*)carve((size_t)MTOT * 128 * 2);
    bf16*  adjB  = (bf16*)carve((size_t)(N04 * 320 + N07 * 896 + N08 * 192) * 2);
    bf16*  W1T   = (bf16*)carve((size_t)3 * 256 * 128 * 2);
    bf16*  W2T   = (bf16*)carve((size_t)3 * 256 * 256 * 2);
    bf16*  featWT= (bf16*)carve((size_t)256 * 256 * 2);
    bf16*  linW2T= (bf16*)carve((size_t)256 * 256 * 2);
    bf16*  outWT = (bf16*)carve((size_t)64 * 256 * 2);
    float* h0F   = (float*)carve((size_t)MTOT * 256 * 4);
    bf16*  h0T   = (bf16*)carve((size_t)256 * H0T_LD * 2);
    float* h1F   = (float*)carve((size_t)MTOT * 256 * 4);
    bf16*  nh1B  = (bf16*)carve((size_t)MTOT * 256 * 2);
    float* degb  = (float*)carve((size_t)MTOT * 4);
    float* mub   = (float*)carve(3 * 256 * 4);
    float* rstdb = (float*)carve(3 * 256 * 4);
    bf16*  f4B   = (bf16*)carve((size_t)N04 * 256 * 2);
    bf16*  fpreB = (bf16*)carve((size_t)N04 * 256 * 2);
    float* fp2   = (float*)carve((size_t)N04 * 256 * 4);

    // --- dtype sniff + canonical fp32 conversion ---
    sniff_kernel<<<1, 256, 0, stream>>>((const unsigned short*)d_in[0], flag);
    Ptrs ptrs;
    for (int i = 0; i < NT; ++i) ptrs.p[i] = d_in[i];
    convert_all<<<g_tbl.blk[NT], 256, 0, stream>>>(ptrs, arena, flag);

    auto A = [&](int i) -> const float* { return arena + g_tbl.off[i]; };

    // --- operand prep ---
    prep_weights<<<1024, 256, 0, stream>>>(A(28), A(30), A(34), WgT, WcT, WlT);
    prep_adjB<<<dim3(N07, 1, 3), 256, 0, stream>>>(A(4), A(5), A(6), adjB);
    prep_transposes<<<(PREP_T_TOT + 255) / 256, 256, 0, stream>>>(
        A(0), A(1), A(2), A(7), A(14), A(21), A(9), A(16), A(23),
        A(32), A(34), A(36), vecB, W1T, W2T, featWT, linW2T, outWT);

    hipMemsetAsync(hb_a, 0, (size_t)BN * HID * 2, stream);
    hipMemsetAsync(h0T, 0, (size_t)256 * H0T_LD * 2, stream);

    const size_t o_f4 = (size_t)B_ * N04 * PRE;
    const size_t o_f7 = o_f4 + (size_t)N04 * ENC;
    const size_t o_f8 = o_f7 + (size_t)N07 * ENC;

    // --- deg ---
    deg_all<<<dim3(N07, 1, 3), 64, 0, stream>>>(A(4), A(5), A(6), degb);

    // --- E1: h0 = vec@W1 + b1 ---
    {
        GemmZ p;
        for (int z = 0; z < 3; ++z) {
            p.A[z] = (const unsigned short*)(vecB + (size_t)c_Moff[z] * 128);
            p.BT[z] = (const unsigned short*)(W1T + (size_t)z * 256 * 128);
            p.M[z] = c_Mi[z]; p.K[z] = 128; p.lda[z] = 128; p.ldb[z] = 128;
        }
        EPg1 ep{{A(8), A(15), A(22)}, h0F, h0T};
        gemm_mfma64<<<dim3(14, 4, 3), 256, 0, stream>>>(p, 256, ep);
    }
    // --- E2: h1 = (adj@h0)/deg + eps*h0 ---
    {
        GemmZ p;
        for (int z = 0; z < 3; ++z) {
            p.A[z] = (const unsigned short*)(adjB + c_Aoff[z]);
            p.BT[z] = (const unsigned short*)(h0T + c_Cb[z]);
            p.M[z] = c_Mi[z]; p.K[z] = c_Kp[z]; p.lda[z] = c_Kp[z]; p.ldb[z] = H0T_LD;
        }
        EPg2 ep{degb, h0F, h1F, {A(13), A(20), A(27)}};
        gemm_mfma64<<<dim3(14, 4, 3), 256, 0, stream>>>(p, 256, ep);
    }
    // --- BN stats + normalize ---
    stats_all<<<dim3(256, 1, 3), 256, 0, stream>>>(h1F, mub, rstdb);
    norm_all<<<MTOT, 256, 0, stream>>>(h1F, mub, rstdb, A(11), A(18), A(25), A(12), A(19), A(26), nh1B);
    // --- E3: f = nh1@W2 + b2 ---
    {
        GemmZ p;
        for (int z = 0; z < 3; ++z) {
            p.A[z] = (const unsigned short*)(nh1B + (size_t)c_Moff[z] * 256);
            p.BT[z] = (const unsigned short*)(W2T + (size_t)z * 256 * 256);
            p.M[z] = c_Mi[z]; p.K[z] = 256; p.lda[z] = 256; p.ldb[z] = 256;
        }
        EPg3 ep{{A(10), A(17), A(24)}, d_out, {o_f4, o_f7, o_f8}, flag, f4B};
        gemm_mfma64<<<dim3(14, 4, 3), 256, 0, stream>>>(p, 256, ep);
    }
    // --- fp2 = (f4@featW + featb) @ linW[256:512] ---
    {
        GemmZ p{};
        p.A[0] = (const unsigned short*)f4B; p.BT[0] = (const unsigned short*)featWT;
        p.M[0] = N04; p.K[0] = 256; p.lda[0] = 256; p.ldb[0] = 256;
        gemm_mfma64<<<dim3(5, 4, 1), 256, 0, stream>>>(p, 256, EPfp2a{A(33), fpreB});
        p.A[0] = (const unsigned short*)fpreB; p.BT[0] = (const unsigned short*)linW2T;
        gemm_mfma64<<<dim3(5, 4, 1), 256, 0, stream>>>(p, 256, EPfp2b{fp2});
    }

    // --- GRU scan: register-B GEMMs (one barrier per block), all-bf16 state ---
    const float* feat = A(3);
    bf16* hcB = hb_a;
    bf16* hnB = hb_b;
    for (int s = 0; s < S_; ++s) {
        gemm_rb<<<dim3(BN / 64, 4), 256, 0, stream>>>(
            (const unsigned short*)hcB, (const unsigned short*)WgT, 512,
            EPgates3{rh, ubufB, hcB, A(29), A(28), feat, s});
        gemm_rb<<<dim3(BN / 64, 2), 256, 0, stream>>>(
            (const unsigned short*)rh, (const unsigned short*)WcT, 256,
            EPcand3{uhc, ubufB, hcB, A(31), A(30), feat, s});
        gemm_rb<<<dim3(BN / 64, 2), 256, 0, stream>>>(
            (const unsigned short*)uhc, (const unsigned short*)WlT, 256,
            EPlin3{hnB, A(35), fp2});
        bf16* tb = hcB; hcB = hnB; hnB = tb;
    }

    // --- pred = h@outW + outb (64-tile kernel, N padded to 64, guard n<12) ---
    {
        GemmZ p{};
        p.A[0] = (const unsigned short*)hcB; p.BT[0] = (const unsigned short*)outWT;
        p.M[0] = BN; p.K[0] = 256; p.lda[0] = 256; p.ldb[0] = 256;
        gemm_mfma64<<<dim3(BN / 64, 1, 1), 256, 0, stream>>>(p, PRE, EPpred{A(37), d_out, flag});
    }
}